// Round 1
// baseline (414.292 us; speedup 1.0000x reference)
//
#include <hip/hip_runtime.h>

// Problem constants (from reference)
#define BB 4
#define CC 256
#define XX 256
#define YY 256
#define NCELLS (BB * XX * YY)   // 262144 cells, 1 MiB of int32

#define CH 32                    // c-channels staged per chunk
#define NCHUNK (CC / CH)         // 8 chunks

// ---------------------------------------------------------------------------
// Kernel 1: fill the cell->row index grid with -1 (int4-vectorized, coalesced)
// ---------------------------------------------------------------------------
__global__ void k_fill_idx(int4* __restrict__ idx4) {
    int i = blockIdx.x * blockDim.x + threadIdx.x;   // NCELLS/4 threads exactly
    idx4[i] = make_int4(-1, -1, -1, -1);
}

// ---------------------------------------------------------------------------
// Kernel 2: scatter row index n into idx[cell]  (coords unique => no races)
// ---------------------------------------------------------------------------
__global__ void k_scatter_idx(const int* __restrict__ coords,
                              int* __restrict__ idx, int n) {
    int i = blockIdx.x * blockDim.x + threadIdx.x;
    if (i >= n) return;
    int b = coords[i * 3 + 0];
    int x = coords[i * 3 + 1];
    int y = coords[i * 3 + 2];
    // mode="drop": out-of-range coords are dropped
    if ((unsigned)b < BB && (unsigned)x < XX && (unsigned)y < YY) {
        idx[(b * XX + x) * YY + y] = i;
    }
}

// ---------------------------------------------------------------------------
// Kernel 3: LDS-staged transpose gather.
// Block = (b,x) slice, 256 threads (4 waves), 4 blocks/CU (16 waves/CU).
// Per 32-c chunk:
//   STAGE: each 8-lane group loads one 128B-aligned, 128B-contiguous segment
//          of one feats row -> every wave load = 8 FULL cache lines, each
//          fetched once and fully consumed by a single instruction.
//          Transpose-write into lds[c][y ^ (c&28)]  (XOR swizzle => 2-way
//          bank access = free; swizzle preserves 16B contiguity/alignment
//          because it only touches y bits [4:2]).
//   DRAIN: wave reads a full 1024B y-line of plane c from LDS (b128,
//          contiguous) and stores it with ONE dwordx4 instruction
//          (1024B/instr fully coalesced global store).
// ---------------------------------------------------------------------------
__global__ __launch_bounds__(256, 4) void k_gather_out(
        const float4* __restrict__ feats4,
        const int*    __restrict__ idx,
        float*        __restrict__ out) {
    __shared__ int   rowid[YY];        // 1 KB: row id per y cell
    __shared__ float lds[CH][YY];      // 32 KB staging tile [c_local][y-swizzled]

    const int bx = blockIdx.x;         // 0 .. B*X-1
    const int t  = threadIdx.x;        // 0 .. 255
    const int b  = bx >> 8;
    const int x  = bx & 255;

    rowid[t] = idx[bx * YY + t];       // coalesced, L2-resident (1 MiB)
    __syncthreads();

    const int lane = t & 63;
    const int w    = t >> 6;           // wave id 0..3
    const int sub  = lane & 7;         // 16B piece within a 128B row segment
    const int g    = lane >> 3;        // row within the 8-row group

    const size_t out_base = ((size_t)b * CC * XX + x) * YY;

    for (int ch = 0; ch < NCHUNK; ++ch) {
        const int c0 = ch * CH;

        // ---- STAGE: 8 float4 loads per thread (8 KB in flight per wave) ----
        #pragma unroll
        for (int j = 0; j < 8; ++j) {
            const int y = w * 64 + j * 8 + g;     // covers all 256 rows/block
            const int r = rowid[y];
            const bool valid = (r >= 0);
            float4 v = feats4[(size_t)(valid ? r : 0) * (CC / 4)
                              + (c0 >> 2) + sub];
            if (!valid) { v.x = 0.f; v.y = 0.f; v.z = 0.f; v.w = 0.f; }
            const int cl = sub * 4;               // c_local of v.x
            const int ys = y ^ (cl & 28);         // swizzle: same for cl..cl+3
            lds[cl + 0][ys] = v.x;
            lds[cl + 1][ys] = v.y;
            lds[cl + 2][ys] = v.z;
            lds[cl + 3][ys] = v.w;
        }
        __syncthreads();

        // ---- DRAIN: 8 plane-lines per wave, 1024B per store instruction ----
        #pragma unroll
        for (int k = 0; k < 8; ++k) {
            const int cl = w * 8 + k;             // 4 waves x 8 = 32 planes
            const int c  = c0 + cl;
            const int ys = (lane * 4) ^ (cl & 28);   // read back swizzled
            const float4 v = *(const float4*)&lds[cl][ys];
            *(float4*)&out[out_base + (size_t)c * (XX * YY) + lane * 4] = v;
        }
        __syncthreads();
    }
}

extern "C" void kernel_launch(void* const* d_in, const int* in_sizes, int n_in,
                              void* d_out, int out_size, void* d_ws, size_t ws_size,
                              hipStream_t stream) {
    const float* feats  = (const float*)d_in[0];   // [N, 256] fp32
    const int*   coords = (const int*)d_in[1];     // [N, 3]   int32
    int n = in_sizes[1] / 3;                       // N = 200000

    int*   idx = (int*)d_ws;                       // 1 MiB scratch
    float* out = (float*)d_out;

    // 1) idx = -1 everywhere (65536 int4 elements)
    k_fill_idx<<<NCELLS / 4 / 256, 256, 0, stream>>>((int4*)idx);

    // 2) scatter row ids into occupied cells
    k_scatter_idx<<<(n + 255) / 256, 256, 0, stream>>>(coords, idx, n);

    // 3) LDS-staged transpose gather: every output element written once
    k_gather_out<<<BB * XX, 256, 0, stream>>>((const float4*)feats, idx, out);
}